// Round 9
// baseline (722.007 us; speedup 1.0000x reference)
//
#include <hip/hip_runtime.h>

typedef unsigned short u16;
typedef unsigned int u32;
typedef __bf16 bf16x8 __attribute__((ext_vector_type(8)));
typedef float f32x4 __attribute__((ext_vector_type(4)));
typedef u16 u16x8 __attribute__((ext_vector_type(8)));

#define IN_CH 256
#define HID 64
#define BSHIFT 8            // 256 nodes per rptr-bucket
#define BNODES 256
#define NBUK 391            // ceil(100000 / 256)
#define BCAP 10240          // mean 8184 edges/bucket; +22 sigma headroom

__device__ __forceinline__ u16 f2bf(float f) {
  union { float f; unsigned u; } v; v.f = f;
  unsigned r = v.u + 0x7FFFu + ((v.u >> 16) & 1u);  // RNE
  return (u16)(r >> 16);
}
__device__ __forceinline__ float bf2f(u16 h) {
  union { unsigned u; float f; } v; v.u = ((unsigned)h) << 16;
  return v.f;
}

// transpose + bf16-convert weights: w1t[n][k] (64x256), w2t[n][k] (64x64)
__global__ void k_wprep(const float* __restrict__ W1, const float* __restrict__ W2,
                        u16* __restrict__ w1t, u16* __restrict__ w2t) {
  int t = blockIdx.x * blockDim.x + threadIdx.x;
  if (t < 64 * 256) {
    int n = t >> 8, k = t & 255;
    w1t[t] = f2bf(W1[k * 64 + n]);
  }
  int t2 = t - 64 * 256;
  if (t2 >= 0 && t2 < 64 * 64) {
    int n = t2 >> 6, k = t2 & 63;
    w2t[t2] = f2bf(W2[k * 64 + n]);
  }
}

// ---------------- direct global counting sort (replaces k_part + k_sort) ----------------
// Round-8 decomposition: part+sort ~= 185 us (over half the runtime), bound by two
// full materialize-shuffle-rewrite passes over the 12.8-MB edge set. Replacement:
// hist (L2-resident 400-KB histogram) + per-bucket local scan + direct scatter.

// 1) per-dst in-degree histogram. 4 edges/thread via int4.
__global__ __launch_bounds__(256) void k_hist(const int* __restrict__ e_dst,
                                              int* __restrict__ hist, int E4) {
  int t = blockIdx.x * blockDim.x + threadIdx.x;
  if (t < E4) {
    int4 d = ((const int4*)e_dst)[t];
    atomicAdd(&hist[d.x], 1);
    atomicAdd(&hist[d.y], 1);
    atomicAdd(&hist[d.z], 1);
    atomicAdd(&hist[d.w], 1);
  }
}

// 2) per-bucket exclusive scan -> rptr/cur/dinv. rptr[node] = bucket*BCAP + scan,
// so no global scan is needed; sedge stays bucketed (16 MB).
__global__ __launch_bounds__(256) void k_rptr(const int* __restrict__ hist,
                                              int* __restrict__ rptr,
                                              int* __restrict__ cur,
                                              float* __restrict__ dinv, int N) {
  __shared__ int wsum[4];
  int b = blockIdx.x, t = threadIdx.x;
  int node = (b << BSHIFT) + t;
  int v = (node < N) ? hist[node] : 0;
  int lane = t & 63, w = t >> 6;
  int x = v;
#pragma unroll
  for (int off = 1; off < 64; off <<= 1) {
    int y = __shfl_up(x, off);
    if (lane >= off) x += y;
  }
  if (lane == 63) wsum[w] = x;
  __syncthreads();
  int wo = 0;
  for (int i = 0; i < w; ++i) wo += wsum[i];
  int ex = x - v + wo;
  if (node < N) {
    int p = b * BCAP + ex;
    rptr[node] = p;
    cur[node] = p;
    dinv[node] = rsqrtf((float)(v + 1));  // +1 self-loop
  }
}

// 3) scatter: sedge[atomicAdd(&cur[d],1)] = src. After this, cur[i] = rptr[i]+deg[i],
// which agg uses as the run end. 4 independent atomic-return chains per thread for ILP.
__global__ __launch_bounds__(256) void k_scatter(const int* __restrict__ e_src,
                                                 const int* __restrict__ e_dst,
                                                 int* __restrict__ cur,
                                                 u32* __restrict__ sedge, int E4) {
  int t = blockIdx.x * blockDim.x + threadIdx.x;
  if (t < E4) {
    int4 d = ((const int4*)e_dst)[t];
    int4 s = ((const int4*)e_src)[t];
    int p0 = atomicAdd(&cur[d.x], 1);
    int p1 = atomicAdd(&cur[d.y], 1);
    int p2 = atomicAdd(&cur[d.z], 1);
    int p3 = atomicAdd(&cur[d.w], 1);
    sedge[p0] = (u32)s.x;
    sedge[p1] = (u32)s.y;
    sedge[p2] = (u32)s.z;
    sedge[p3] = (u32)s.w;
  }
}

// ---------------- gemm1 (MFMA 16x16x32 bf16), wave = 16 rows x ALL 64 cols ----------------
// A[m=lane&15][k=quad*8+j], B[n=lane&15][k=quad*8+j], D: col=lane&15, row=quad*4+reg.
// h'[row] = dinv[row] * (x@W1)[row].
// launch_bounds(256,1): frees the register allocator so the 16 hoisted A-loads
// stay clustered (tighter bound previously serialized them -> latency-bound).

__global__ __launch_bounds__(256, 1) void k_gemm1(const float* __restrict__ x,
                                                  const u16* __restrict__ w1t,
                                                  const float* __restrict__ dinv,
                                                  u16* __restrict__ h1, int N) {
  int lane = threadIdx.x & 63;
  int wave = threadIdx.x >> 6;
  int rowbase = (blockIdx.x * 4 + wave) * 16;
  if (rowbase >= N) return;  // N % 16 == 0: tiles never straddle
  int mn = lane & 15, quad = lane >> 4;
  const float* arow = x + (size_t)(rowbase + mn) * IN_CH + quad * 8;

  // hoist all 16 A loads (64 VGPR) -> one vmcnt wait
  float4 a[16];
#pragma unroll
  for (int kc = 0; kc < 8; ++kc) {
    a[2 * kc] = *(const float4*)(arow + kc * 32);
    a[2 * kc + 1] = *(const float4*)(arow + kc * 32 + 4);
  }
  // convert once to bf16 frags (32 VGPR)
  u16x8 au[8];
#pragma unroll
  for (int kc = 0; kc < 8; ++kc) {
    float4 a0 = a[2 * kc], a1 = a[2 * kc + 1];
    au[kc][0] = f2bf(a0.x); au[kc][1] = f2bf(a0.y);
    au[kc][2] = f2bf(a0.z); au[kc][3] = f2bf(a0.w);
    au[kc][4] = f2bf(a1.x); au[kc][5] = f2bf(a1.y);
    au[kc][6] = f2bf(a1.z); au[kc][7] = f2bf(a1.w);
  }

  f32x4 acc[4] = {{0.f, 0.f, 0.f, 0.f}, {0.f, 0.f, 0.f, 0.f},
                  {0.f, 0.f, 0.f, 0.f}, {0.f, 0.f, 0.f, 0.f}};
#pragma unroll
  for (int c = 0; c < 4; ++c) {
    const u16* brow = w1t + (c * 16 + mn) * IN_CH + quad * 8;
    u16x8 bu[8];  // clustered, L1-hot (B is 32 KB shared chip-wide)
#pragma unroll
    for (int kc = 0; kc < 8; ++kc) bu[kc] = *(const u16x8*)(brow + kc * 32);
#pragma unroll
    for (int kc = 0; kc < 8; ++kc)
      acc[c] = __builtin_amdgcn_mfma_f32_16x16x32_bf16(
          __builtin_bit_cast(bf16x8, au[kc]), __builtin_bit_cast(bf16x8, bu[kc]),
          acc[c], 0, 0, 0);
  }
#pragma unroll
  for (int r = 0; r < 4; ++r) {
    int row = rowbase + quad * 4 + r;
    float dv = dinv[row];
#pragma unroll
    for (int c = 0; c < 4; ++c)
      h1[(size_t)row * HID + c * 16 + mn] = f2bf(dv * acc[c][r]);
  }
}

__global__ __launch_bounds__(256) void k_gemm2(const u16* __restrict__ g1,
                                               const u16* __restrict__ w2t,
                                               const float* __restrict__ dinv,
                                               u16* __restrict__ h2) {
  int lane = threadIdx.x & 63;
  int wave = threadIdx.x >> 6;
  int rowbase = blockIdx.x * 16;
  int colbase = wave * 16;
  int mn = lane & 15, quad = lane >> 4;
  const u16* arow = g1 + (size_t)(rowbase + mn) * HID + quad * 8;
  const u16* brow = w2t + (colbase + mn) * HID + quad * 8;
  u16x8 au0 = *(const u16x8*)(arow);
  u16x8 au1 = *(const u16x8*)(arow + 32);
  u16x8 bu0 = *(const u16x8*)(brow);
  u16x8 bu1 = *(const u16x8*)(brow + 32);
  f32x4 acc = {0.f, 0.f, 0.f, 0.f};
  acc = __builtin_amdgcn_mfma_f32_16x16x32_bf16(
      __builtin_bit_cast(bf16x8, au0), __builtin_bit_cast(bf16x8, bu0), acc, 0, 0, 0);
  acc = __builtin_amdgcn_mfma_f32_16x16x32_bf16(
      __builtin_bit_cast(bf16x8, au1), __builtin_bit_cast(bf16x8, bu1), acc, 0, 0, 0);
#pragma unroll
  for (int r = 0; r < 4; ++r) {
    int row = rowbase + quad * 4 + r;
    h2[(size_t)row * HID + colbase + mn] = f2bf(dinv[row] * acc[r]);
  }
}

// ---------------- aggregation: wave per node, scalar edges, multi-accumulator ----------------
// out[i] = dinv_i * (sum_e h'[src_e] + h'[i]) + bias
// The proven ~58-64us/pass form (L2-miss-transaction-bound). Run bounds come from
// rptr (start) and cur (end = rptr+deg, left by k_scatter). sedge holds raw src ids.

template <bool RELU, bool BF16OUT>
__global__ __launch_bounds__(256, 4) void k_agg(const u16* __restrict__ hin,
                                                const int* __restrict__ rptr,
                                                const int* __restrict__ cur,
                                                const u32* __restrict__ sedge,
                                                const float* __restrict__ bias,
                                                void* __restrict__ outv, int N) {
  int wid = blockIdx.x * 4 + (threadIdx.x >> 6);
  int lane = threadIdx.x & 63;
  if (wid >= N) return;
  int start = __builtin_amdgcn_readfirstlane(rptr[wid]);
  int len = __builtin_amdgcn_readfirstlane(cur[wid]) - start;
  float di = rsqrtf((float)(len + 1));
  float a0 = bf2f(hin[(size_t)wid * HID + lane]);  // self-loop
  float a1 = 0.f, a2 = 0.f, a3 = 0.f;
  const u32* se = sedge + start;
  int j = 0;
  for (; j + 16 <= len; j += 16) {
    u16 v[16];
#pragma unroll
    for (int k = 0; k < 16; ++k) {
      int e = (int)se[j + k];              // wave-uniform -> s_load batch
      v[k] = hin[(size_t)e * HID + lane];  // 16 gathers in flight
    }
#pragma unroll
    for (int k = 0; k < 16; ++k) {
      float f = bf2f(v[k]);
      if ((k & 3) == 0) a0 += f;
      else if ((k & 3) == 1) a1 += f;
      else if ((k & 3) == 2) a2 += f;
      else a3 += f;
    }
  }
  if (j + 8 <= len) {
    u16 v[8];
#pragma unroll
    for (int k = 0; k < 8; ++k) {
      int e = (int)se[j + k];
      v[k] = hin[(size_t)e * HID + lane];
    }
#pragma unroll
    for (int k = 0; k < 8; ++k) {
      float f = bf2f(v[k]);
      if ((k & 3) == 0) a0 += f;
      else if ((k & 3) == 1) a1 += f;
      else if ((k & 3) == 2) a2 += f;
      else a3 += f;
    }
    j += 8;
  }
  if (j + 4 <= len) {
    u16 v[4];
#pragma unroll
    for (int k = 0; k < 4; ++k) {
      int e = (int)se[j + k];
      v[k] = hin[(size_t)e * HID + lane];
    }
    a0 += bf2f(v[0]); a1 += bf2f(v[1]); a2 += bf2f(v[2]); a3 += bf2f(v[3]);
    j += 4;
  }
  for (; j < len; ++j) {
    int e = (int)se[j];
    a0 += bf2f(hin[(size_t)e * HID + lane]);
  }
  float acc = (a0 + a1) + (a2 + a3);
  acc = di * acc + bias[lane];
  if (RELU) acc = fmaxf(acc, 0.f);
  if (BF16OUT) ((u16*)outv)[(size_t)wid * HID + lane] = f2bf(acc);
  else ((float*)outv)[(size_t)wid * HID + lane] = acc;
}

// ---------------- host ----------------

extern "C" void kernel_launch(void* const* d_in, const int* in_sizes, int n_in,
                              void* d_out, int out_size, void* d_ws, size_t ws_size,
                              hipStream_t stream) {
  const float* x = (const float*)d_in[0];
  const int* ei = (const int*)d_in[1];  // [2][E] int32
  const float* W1 = (const float*)d_in[2];
  const float* b1 = (const float*)d_in[3];
  const float* W2 = (const float*)d_in[4];
  const float* b2 = (const float*)d_in[5];
  float* out = (float*)d_out;

  const int N = in_sizes[0] / IN_CH;  // 100000
  const int E = in_sizes[1] / 2;      // 3200000
  const int* e_src = ei;
  const int* e_dst = ei + E;

  size_t off = 0;
  auto carve = [&](size_t bytes) -> char* {
    char* p = (char*)d_ws + off;
    off += (bytes + 255) & ~(size_t)255;
    return p;
  };
  int* hist = (int*)carve((size_t)N * 4);
  int* rptr = (int*)carve((size_t)N * 4);
  int* cur = (int*)carve((size_t)N * 4);
  float* dinv = (float*)carve((size_t)N * 4);
  u32* sedge = (u32*)carve((size_t)NBUK * BCAP * 4);  // 16 MB
  u16* w1t = (u16*)carve(64 * 256 * 2);
  u16* w2t = (u16*)carve(64 * 64 * 2);
  u16* h1 = (u16*)carve((size_t)N * HID * 2);  // reused for h2
  u16* g1 = (u16*)carve((size_t)N * HID * 2);

  const int E4 = E / 4;                       // 800000 (E % 4 == 0)
  const int nb_e4 = (E4 + 255) / 256;         // 3125
  const int nb_g1 = (N + 63) / 64;            // 64 rows per block (4 waves x 16)

  (void)hipMemsetAsync(hist, 0, (size_t)N * 4, stream);
  k_wprep<<<(64 * 256 + 64 * 64 + 255) / 256, 256, 0, stream>>>(W1, W2, w1t, w2t);
  k_hist<<<nb_e4, 256, 0, stream>>>(e_dst, hist, E4);
  k_rptr<<<NBUK, 256, 0, stream>>>(hist, rptr, cur, dinv, N);
  k_scatter<<<nb_e4, 256, 0, stream>>>(e_src, e_dst, cur, sedge, E4);
  k_gemm1<<<nb_g1, 256, 0, stream>>>(x, w1t, dinv, h1, N);
  k_agg<true, true><<<(N + 3) / 4, 256, 0, stream>>>(h1, rptr, cur, sedge, b1, g1, N);
  k_gemm2<<<N / 16, 256, 0, stream>>>(g1, w2t, dinv, h1);
  k_agg<false, false><<<(N + 3) / 4, 256, 0, stream>>>(h1, rptr, cur, sedge, b2, out, N);
}

// Round 10
// 345.675 us; speedup vs baseline: 2.0887x; 2.0887x over previous
//
#include <hip/hip_runtime.h>

typedef unsigned short u16;
typedef unsigned int u32;
typedef __bf16 bf16x8 __attribute__((ext_vector_type(8)));
typedef float f32x4 __attribute__((ext_vector_type(4)));
typedef u16 u16x8 __attribute__((ext_vector_type(8)));

#define IN_CH 256
#define HID 64
#define BSHIFT 7            // 128 nodes per bucket
#define BNODES 128
#define NBUK 782            // ceil(100000 / 128)
#define BCAP 5632           // mean 4092 edges/bucket; +24 sigma headroom
#define TILE 8192           // edges per partition tile

__device__ __forceinline__ u16 f2bf(float f) {
  union { float f; unsigned u; } v; v.f = f;
  unsigned r = v.u + 0x7FFFu + ((v.u >> 16) & 1u);  // RNE
  return (u16)(r >> 16);
}
__device__ __forceinline__ float bf2f(u16 h) {
  union { unsigned u; float f; } v; v.u = ((unsigned)h) << 16;
  return v.f;
}

// W1 transpose + bf16 convert, AND zero bcnt (absorbs the old hipMemsetAsync
// dispatch; ~10us/dispatch drain overhead measured across rounds 5/8).
__global__ void k_wprep(const float* __restrict__ W1, u16* __restrict__ w1t,
                        int* __restrict__ bcnt) {
  int t = blockIdx.x * blockDim.x + threadIdx.x;
  if (t < 64 * 256) {
    int n = t >> 8, k = t & 255;
    w1t[t] = f2bf(W1[k * 64 + n]);
  }
  if (t < NBUK) bcnt[t] = 0;
}

// ---------------- phase A: LDS-staged bucket partition (128-node buckets) ----------------
// Edge packed as u32: src (bits 0-19) | dloc (bits 20-26). Proven in round 8.

__global__ __launch_bounds__(1024) void k_part(const int* __restrict__ e_src,
                                               const int* __restrict__ e_dst,
                                               int* __restrict__ bcnt,
                                               u32* __restrict__ bedge, int E) {
  __shared__ int lcnt[1024];
  __shared__ int lscan[1024];
  __shared__ int gbase[1024];
  __shared__ int wsum[16];
  __shared__ u32 stag[TILE];
  __shared__ int dest[TILE];
  int t = threadIdx.x;
  int base = blockIdx.x * TILE;
  int here = E - base; if (here > TILE) here = TILE;

  lcnt[t] = 0;
  __syncthreads();

  u32 m[8]; int bk[8]; int rk[8];
#pragma unroll
  for (int k = 0; k < 8; ++k) {
    int e = base + t + k * 1024;
    if (e < E) {
      int s = e_src[e], d = e_dst[e];
      bk[k] = d >> BSHIFT;
      m[k] = (u32)s | ((u32)(d & (BNODES - 1)) << 20);
      rk[k] = atomicAdd(&lcnt[bk[k]], 1);
    } else bk[k] = -1;
  }
  __syncthreads();

  // exclusive scan of lcnt[0..1023] (16 waves)
  int lane = t & 63, w = t >> 6;
  int v = lcnt[t], x = v;
#pragma unroll
  for (int off = 1; off < 64; off <<= 1) {
    int y = __shfl_up(x, off);
    if (lane >= off) x += y;
  }
  if (lane == 63) wsum[w] = x;
  __syncthreads();
  {
    int wo = 0;
    for (int i = 0; i < w; ++i) wo += wsum[i];
    lscan[t] = x - v + wo;
  }
  __syncthreads();

  // reserve global space per bucket
  if (t < NBUK) gbase[t] = t * BCAP + atomicAdd(&bcnt[t], lcnt[t]);
  __syncthreads();

  // place into LDS staging ordered by bucket
#pragma unroll
  for (int k = 0; k < 8; ++k) {
    if (bk[k] >= 0) {
      int p = lscan[bk[k]] + rk[k];
      stag[p] = m[k];
      dest[p] = gbase[bk[k]] + rk[k];
    }
  }
  __syncthreads();

  // coalesced copy-out (runs of same-bucket edges are contiguous)
#pragma unroll
  for (int k = 0; k < 8; ++k) {
    int p = t + k * 1024;
    if (p < here) bedge[dest[p]] = stag[p];
  }
}

// ---------------- phase B: per-bucket counting sort by dst (in-place) ----------------
// Emits rptr/rcnt/dinv. Proven round-8 geometry: 782 x 512 x 24 KB.

__global__ __launch_bounds__(512) void k_sort(const int* __restrict__ bcnt,
                                              u32* __restrict__ bedge,
                                              int* __restrict__ rptr,
                                              int* __restrict__ rcnt,
                                              float* __restrict__ dinv, int N) {
  __shared__ u32 stag[BCAP];     // 22 KB
  __shared__ int hist[BNODES];
  __shared__ int cur[BNODES];
  __shared__ int wsum2[2];
  int b = blockIdx.x, t = threadIdx.x;
  if (t < BNODES) hist[t] = 0;
  __syncthreads();
  int n = bcnt[b]; if (n > BCAP) n = BCAP;
  u32* be = bedge + (size_t)b * BCAP;

  for (int i = t; i < n; i += 512) atomicAdd(&hist[be[i] >> 20], 1);
  __syncthreads();

  // exclusive scan of hist[0..127] by threads 0..127 (2 waves)
  int lane = t & 63, w = t >> 6;
  int v = 0, x = 0;
  if (t < BNODES) { v = hist[t]; x = v; }
#pragma unroll
  for (int off = 1; off < 64; off <<= 1) {
    int y = __shfl_up(x, off);
    if (lane >= off) x += y;
  }
  if (t < BNODES && lane == 63) wsum2[w] = x;
  __syncthreads();
  if (t < BNODES) {
    int wo = (w == 1) ? wsum2[0] : 0;
    int ex = x - v + wo;
    cur[t] = ex;
    int node = (b << BSHIFT) + t;
    if (node < N) {
      rptr[node] = b * BCAP + ex;
      rcnt[node] = v;
      dinv[node] = rsqrtf((float)(v + 1));  // +1 self-loop
    }
  }
  __syncthreads();

  // rank + scatter into LDS (sorted by dloc)
  for (int i = t; i < n; i += 512) {
    u32 m = be[i];
    int p = atomicAdd(&cur[m >> 20], 1);
    stag[p] = m;
  }
  __syncthreads();

  // in-place coalesced writeback
  for (int i = t; i < n; i += 512) be[i] = stag[i];
}

// ---------------- gemm1 (MFMA 16x16x32 bf16), wave = 16 rows x ALL 64 cols ----------------
// h'[row] = dinv[row] * (x@W1)[row]. Proven form.

__global__ __launch_bounds__(256, 1) void k_gemm1(const float* __restrict__ x,
                                                  const u16* __restrict__ w1t,
                                                  const float* __restrict__ dinv,
                                                  u16* __restrict__ h1, int N) {
  int lane = threadIdx.x & 63;
  int wave = threadIdx.x >> 6;
  int rowbase = (blockIdx.x * 4 + wave) * 16;
  if (rowbase >= N) return;  // N % 16 == 0: tiles never straddle
  int mn = lane & 15, quad = lane >> 4;
  const float* arow = x + (size_t)(rowbase + mn) * IN_CH + quad * 8;

  // hoist all 16 A loads (64 VGPR) -> one vmcnt wait
  float4 a[16];
#pragma unroll
  for (int kc = 0; kc < 8; ++kc) {
    a[2 * kc] = *(const float4*)(arow + kc * 32);
    a[2 * kc + 1] = *(const float4*)(arow + kc * 32 + 4);
  }
  // convert once to bf16 frags (32 VGPR)
  u16x8 au[8];
#pragma unroll
  for (int kc = 0; kc < 8; ++kc) {
    float4 a0 = a[2 * kc], a1 = a[2 * kc + 1];
    au[kc][0] = f2bf(a0.x); au[kc][1] = f2bf(a0.y);
    au[kc][2] = f2bf(a0.z); au[kc][3] = f2bf(a0.w);
    au[kc][4] = f2bf(a1.x); au[kc][5] = f2bf(a1.y);
    au[kc][6] = f2bf(a1.z); au[kc][7] = f2bf(a1.w);
  }

  f32x4 acc[4] = {{0.f, 0.f, 0.f, 0.f}, {0.f, 0.f, 0.f, 0.f},
                  {0.f, 0.f, 0.f, 0.f}, {0.f, 0.f, 0.f, 0.f}};
#pragma unroll
  for (int c = 0; c < 4; ++c) {
    const u16* brow = w1t + (c * 16 + mn) * IN_CH + quad * 8;
    u16x8 bu[8];  // clustered, L1-hot (B is 32 KB shared chip-wide)
#pragma unroll
    for (int kc = 0; kc < 8; ++kc) bu[kc] = *(const u16x8*)(brow + kc * 32);
#pragma unroll
    for (int kc = 0; kc < 8; ++kc)
      acc[c] = __builtin_amdgcn_mfma_f32_16x16x32_bf16(
          __builtin_bit_cast(bf16x8, au[kc]), __builtin_bit_cast(bf16x8, bu[kc]),
          acc[c], 0, 0, 0);
  }
#pragma unroll
  for (int r = 0; r < 4; ++r) {
    int row = rowbase + quad * 4 + r;
    float dv = dinv[row];
#pragma unroll
    for (int c = 0; c < 4; ++c)
      h1[(size_t)row * HID + c * 16 + mn] = f2bf(dv * acc[c][r]);
  }
}

// ---------------- agg pass 1: wave per node, proven gather loop ----------------
// u[i] = dinv_i * relu( dinv_i * (sum_e h'[src_e] + h'[i]) + b1 )
// Pre-applies the source-side norm for layer 2 (linearity fusion, verified
// numerically in round 5), so agg2 can fold @W2 into its epilogue.

__global__ __launch_bounds__(256, 4) void k_agg1(const u16* __restrict__ hin,
                                                 const int* __restrict__ rptr,
                                                 const int* __restrict__ rcnt,
                                                 const u32* __restrict__ sedge,
                                                 const float* __restrict__ bias,
                                                 u16* __restrict__ outu, int N) {
  int wid = blockIdx.x * 4 + (threadIdx.x >> 6);
  int lane = threadIdx.x & 63;
  if (wid >= N) return;
  int start = __builtin_amdgcn_readfirstlane(rptr[wid]);
  int len = __builtin_amdgcn_readfirstlane(rcnt[wid]);
  float di = rsqrtf((float)(len + 1));
  float a0 = bf2f(hin[(size_t)wid * HID + lane]);  // self-loop
  float a1 = 0.f, a2 = 0.f, a3 = 0.f;
  const u32* se = sedge + start;
  int j = 0;
  for (; j + 16 <= len; j += 16) {
    u16 v[16];
#pragma unroll
    for (int k = 0; k < 16; ++k) {
      int e = (int)(se[j + k] & 0xFFFFF);  // wave-uniform -> s_load batch
      v[k] = hin[(size_t)e * HID + lane];  // 16 gathers in flight
    }
#pragma unroll
    for (int k = 0; k < 16; ++k) {
      float f = bf2f(v[k]);
      if ((k & 3) == 0) a0 += f;
      else if ((k & 3) == 1) a1 += f;
      else if ((k & 3) == 2) a2 += f;
      else a3 += f;
    }
  }
  if (j + 8 <= len) {
    u16 v[8];
#pragma unroll
    for (int k = 0; k < 8; ++k) {
      int e = (int)(se[j + k] & 0xFFFFF);
      v[k] = hin[(size_t)e * HID + lane];
    }
#pragma unroll
    for (int k = 0; k < 8; ++k) {
      float f = bf2f(v[k]);
      if ((k & 3) == 0) a0 += f;
      else if ((k & 3) == 1) a1 += f;
      else if ((k & 3) == 2) a2 += f;
      else a3 += f;
    }
    j += 8;
  }
  if (j + 4 <= len) {
    u16 v[4];
#pragma unroll
    for (int k = 0; k < 4; ++k) {
      int e = (int)(se[j + k] & 0xFFFFF);
      v[k] = hin[(size_t)e * HID + lane];
    }
    a0 += bf2f(v[0]); a1 += bf2f(v[1]); a2 += bf2f(v[2]); a3 += bf2f(v[3]);
    j += 4;
  }
  for (; j < len; ++j) {
    int e = (int)(se[j] & 0xFFFFF);
    a0 += bf2f(hin[(size_t)e * HID + lane]);
  }
  float acc = (a0 + a1) + (a2 + a3);
  acc = fmaxf(di * acc + bias[lane], 0.f);   // relu
  outu[(size_t)wid * HID + lane] = f2bf(di * acc);  // pre-scaled u row
}

// ---------------- agg pass 2 + fused @W2: SAME 256-thread/4-wave geometry ----------------
// out[i] = dinv_i * ((sum_e u[src_e] + u[i]) @ W2) + b2
// Round-5's 92us failure was the 1024-thread/16-wave geometry (max-of-16 tail +
// barrier over 16 waves), not the fusion. Here: 4 waves, N%4==0 so every thread
// reaches the one barrier; W2 in 8-KB bf16 LDS (broadcast, L2-hot across 25K
// blocks); epilogue dot: rowbuf[wave][k] broadcast read x w2s stride-1 read,
// conflict-free. Kills gemm2 + w2t prep + 26 MB of h2 traffic + 2 dispatches.

__global__ __launch_bounds__(256, 4) void k_agg2(const u16* __restrict__ u1,
                                                 const int* __restrict__ rptr,
                                                 const int* __restrict__ rcnt,
                                                 const u32* __restrict__ sedge,
                                                 const float* __restrict__ W2,
                                                 const float* __restrict__ b2,
                                                 float* __restrict__ out, int N) {
  __shared__ u16 w2s[HID * HID];    // 8 KB, [k][n] = W2 row-major
  __shared__ float rowbuf[4][HID];  // 1 KB
  int t = threadIdx.x;
#pragma unroll
  for (int i = 0; i < 16; ++i) w2s[t + i * 256] = f2bf(W2[t + i * 256]);
  __syncthreads();
  int wave = t >> 6, lane = t & 63;
  int wid = blockIdx.x * 4 + wave;   // N % 4 == 0: never out of range
  int start = __builtin_amdgcn_readfirstlane(rptr[wid]);
  int len = __builtin_amdgcn_readfirstlane(rcnt[wid]);
  float di = rsqrtf((float)(len + 1));
  float a0 = bf2f(u1[(size_t)wid * HID + lane]);  // self-loop u row
  float a1 = 0.f, a2 = 0.f, a3 = 0.f;
  const u32* se = sedge + start;
  int j = 0;
  for (; j + 16 <= len; j += 16) {
    u16 v[16];
#pragma unroll
    for (int k = 0; k < 16; ++k) {
      int e = (int)(se[j + k] & 0xFFFFF);
      v[k] = u1[(size_t)e * HID + lane];
    }
#pragma unroll
    for (int k = 0; k < 16; ++k) {
      float f = bf2f(v[k]);
      if ((k & 3) == 0) a0 += f;
      else if ((k & 3) == 1) a1 += f;
      else if ((k & 3) == 2) a2 += f;
      else a3 += f;
    }
  }
  if (j + 8 <= len) {
    u16 v[8];
#pragma unroll
    for (int k = 0; k < 8; ++k) {
      int e = (int)(se[j + k] & 0xFFFFF);
      v[k] = u1[(size_t)e * HID + lane];
    }
#pragma unroll
    for (int k = 0; k < 8; ++k) {
      float f = bf2f(v[k]);
      if ((k & 3) == 0) a0 += f;
      else if ((k & 3) == 1) a1 += f;
      else if ((k & 3) == 2) a2 += f;
      else a3 += f;
    }
    j += 8;
  }
  if (j + 4 <= len) {
    u16 v[4];
#pragma unroll
    for (int k = 0; k < 4; ++k) {
      int e = (int)(se[j + k] & 0xFFFFF);
      v[k] = u1[(size_t)e * HID + lane];
    }
    a0 += bf2f(v[0]); a1 += bf2f(v[1]); a2 += bf2f(v[2]); a3 += bf2f(v[3]);
    j += 4;
  }
  for (; j < len; ++j) {
    int e = (int)(se[j] & 0xFFFFF);
    a0 += bf2f(u1[(size_t)e * HID + lane]);
  }
  float acc = (a0 + a1) + (a2 + a3);

  // fused @W2 (wave-local; compiler inserts the lgkmcnt dep-wait)
  rowbuf[wave][lane] = acc;
  float o = 0.f;
#pragma unroll 8
  for (int k = 0; k < HID; ++k)
    o += rowbuf[wave][k] * bf2f(w2s[k * HID + lane]);
  out[(size_t)wid * HID + lane] = di * o + b2[lane];
}

// ---------------- host ----------------

extern "C" void kernel_launch(void* const* d_in, const int* in_sizes, int n_in,
                              void* d_out, int out_size, void* d_ws, size_t ws_size,
                              hipStream_t stream) {
  const float* x = (const float*)d_in[0];
  const int* ei = (const int*)d_in[1];  // [2][E] int32
  const float* W1 = (const float*)d_in[2];
  const float* b1 = (const float*)d_in[3];
  const float* W2 = (const float*)d_in[4];
  const float* b2 = (const float*)d_in[5];
  float* out = (float*)d_out;

  const int N = in_sizes[0] / IN_CH;  // 100000
  const int E = in_sizes[1] / 2;      // 3200000
  const int* e_src = ei;
  const int* e_dst = ei + E;

  size_t off = 0;
  auto carve = [&](size_t bytes) -> char* {
    char* p = (char*)d_ws + off;
    off += (bytes + 255) & ~(size_t)255;
    return p;
  };
  int* bcnt = (int*)carve((size_t)NBUK * 4);
  u32* bedge = (u32*)carve((size_t)NBUK * BCAP * 4);  // 17.6 MB
  int* rptr = (int*)carve((size_t)N * 4);
  int* rcnt = (int*)carve((size_t)N * 4);
  float* dinv = (float*)carve((size_t)N * 4);
  u16* w1t = (u16*)carve(64 * 256 * 2);
  u16* h1 = (u16*)carve((size_t)N * HID * 2);
  u16* u1 = (u16*)carve((size_t)N * HID * 2);

  const int n_tiles = (E + TILE - 1) / TILE;  // 391
  const int nb_g1 = (N + 63) / 64;            // 64 rows per block (4 waves x 16)

  k_wprep<<<(64 * 256 + 255) / 256, 256, 0, stream>>>(W1, w1t, bcnt);
  k_part<<<n_tiles, 1024, 0, stream>>>(e_src, e_dst, bcnt, bedge, E);
  k_sort<<<NBUK, 512, 0, stream>>>(bcnt, bedge, rptr, rcnt, dinv, N);
  k_gemm1<<<nb_g1, 256, 0, stream>>>(x, w1t, dinv, h1, N);
  k_agg1<<<N / 4, 256, 0, stream>>>(h1, rptr, rcnt, bedge, b1, u1, N);
  k_agg2<<<N / 4, 256, 0, stream>>>(u1, rptr, rcnt, bedge, W2, b2, out, N);
}